// Round 19
// baseline (221.255 us; speedup 1.0000x reference)
//
#include <hip/hip_runtime.h>
#include <hip/hip_bf16.h>
#include <cstdint>

#define B_ 256
#define T_ 600
#define D_ 256

typedef __attribute__((ext_vector_type(8))) short bf16x8;
typedef __attribute__((ext_vector_type(4))) float f32x4;

__device__ __forceinline__ float fast_sigmoid(float x) {
    return __fdividef(1.0f, 1.0f + __expf(-x));
}
__device__ __forceinline__ float fast_tanh(float x) {
    return 1.0f - __fdividef(2.0f, __expf(2.0f * x) + 1.0f);
}
__device__ __forceinline__ ushort f2bf(float f) {
    unsigned u = __float_as_uint(f);
    u += 0x7FFF + ((u >> 16) & 1);   // round-to-nearest-even
    return (ushort)(u >> 16);
}
__device__ __forceinline__ float bf2f(ushort u) {
    return __uint_as_float((unsigned)u << 16);
}

// ---------------------------------------------------------------------------
// prenet: init_concat (bf16 Xgru16 / Xrnn16 parts) + prenet MLP + Lw16 pack
// ---------------------------------------------------------------------------
__global__ __launch_bounds__(256) void prenet_kernel(
    const float* __restrict__ pre_in, const float* __restrict__ noise,
    const float* __restrict__ w1, const float* __restrict__ b1,
    const float* __restrict__ w2, const float* __restrict__ b2,
    const float* __restrict__ ctx_in, const float* __restrict__ spk,
    const float* __restrict__ L_w, ushort* __restrict__ Lw16,
    ushort* __restrict__ Xgru16, ushort* __restrict__ Xrnn16)
{
    __shared__ float xin[144];
    __shared__ float p1[256];
    int b = blockIdx.x, t = threadIdx.x;
    if (b == 0) {
        for (int o = t; o < 8192; o += 256) {
            int dt = o >> 9;
            int ln = (o >> 3) & 63;
            int j  = o & 7;
            int in_idx = (dt * 16 + (ln & 15)) * 32 + (ln >> 4) * 8 + j;
            Lw16[o] = f2bf(L_w[in_idx]);
        }
    }
    float s = spk[b * 256 + t];
    Xgru16[b * 640 + t] = f2bf(ctx_in[b * 256 + t]);
    Xgru16[b * 640 + 384 + t] = f2bf(s);
    Xrnn16[b * 832 + 512 + t] = f2bf(s);
    if (t < 64) Xrnn16[b * 832 + 768 + t] = f2bf(noise[b * 64 + t]);
    if (t < 80) xin[t] = pre_in[b * 80 + t];
    else if (t < 144) xin[t] = noise[b * 64 + (t - 80)];
    __syncthreads();
    float acc = b1[t];
    const float4* w = (const float4*)(w1 + t * 144);
    const float4* xi = (const float4*)xin;
#pragma unroll 9
    for (int k = 0; k < 36; ++k) {
        float4 wv = w[k]; float4 xv = xi[k];
        acc += wv.x * xv.x + wv.y * xv.y + wv.z * xv.z + wv.w * xv.w;
    }
    p1[t] = fmaxf(acc, 0.f);
    __syncthreads();
    if (t < 128) {
        float a2 = b2[t];
        const float4* w2v = (const float4*)(w2 + t * 256);
        const float4* pv = (const float4*)p1;
#pragma unroll 8
        for (int k = 0; k < 64; ++k) {
            float4 wv = w2v[k]; float4 xv = pv[k];
            a2 += wv.x * xv.x + wv.y * xv.y + wv.z * xv.z + wv.w * xv.w;
        }
        Xgru16[b * 640 + 256 + t] = f2bf(fmaxf(a2, 0.f));
    }
}

// ---------------------------------------------------------------------------
// convert_all: every weight/input cast to bf16 in one launch.
// ---------------------------------------------------------------------------
__global__ __launch_bounds__(256) void convert_all(
    const float* __restrict__ w1ih, const float* __restrict__ w1hh,
    const float* __restrict__ w2ih, const float* __restrict__ w2hh,
    const float* __restrict__ gwih, const float* __restrict__ gwhh,
    const float* __restrict__ Ww, const float* __restrict__ riw,
    const float* __restrict__ ahin, const float* __restrict__ h1in,
    ushort* __restrict__ wcat1, ushort* __restrict__ wcat2,
    ushort* __restrict__ gwih16, ushort* __restrict__ gwhh16,
    ushort* __restrict__ Ww16, ushort* __restrict__ riw16,
    ushort* __restrict__ ahin16, ushort* __restrict__ xh1)
{
    int bid = blockIdx.x, t = threadIdx.x;
    if (bid < 4096) {
        int n = bid & 2047;
        int layer = bid >> 11;
        const float* wih = layer ? w2ih : w1ih;
        const float* whh = layer ? w2hh : w1hh;
        ushort* dst = layer ? wcat2 : wcat1;
        const float* src = (t < 128) ? (wih + (size_t)n * 512 + t * 4)
                                     : (whh + (size_t)n * 512 + (t - 128) * 4);
        float4 v = *(const float4*)src;
        ushort4 o;
        o.x = f2bf(v.x); o.y = f2bf(v.y); o.z = f2bf(v.z); o.w = f2bf(v.w);
        *(ushort4*)&dst[(size_t)n * 1024 + t * 4] = o;
        return;
    }
    bid -= 4096;
    if (bid >= 1216) {           // h1_in -> xh1[:,512:1024)
        bid -= 1216;
        size_t i = (size_t)bid * 1024 + t * 4;
        float4 v = *(const float4*)&h1in[i];
        int b = (int)(i >> 9), k = (int)(i & 511);
        ushort4 o;
        o.x = f2bf(v.x); o.y = f2bf(v.y); o.z = f2bf(v.z); o.w = f2bf(v.w);
        *(ushort4*)&xh1[(size_t)b * 1024 + 512 + k] = o;
        return;
    }
    const float* src; ushort* dst;
    if (bid < 480)       { src = gwih; dst = gwih16; }
    else if (bid < 672)  { bid -= 480;  src = gwhh; dst = gwhh16; }
    else if (bid < 736)  { bid -= 672;  src = Ww;   dst = Ww16; }
    else if (bid < 1152) { bid -= 736;  src = riw;  dst = riw16; }
    else                 { bid -= 1152; src = ahin; dst = ahin16; }
    size_t i = (size_t)bid * 1024 + t * 4;
    float4 v = *(const float4*)&src[i];
    ushort4 o;
    o.x = f2bf(v.x); o.y = f2bf(v.y); o.z = f2bf(v.z); o.w = f2bf(v.w);
    *(ushort4*)&dst[i] = o;
}

// ---------------------------------------------------------------------------
// mfma_gemmN: C[256,N] = A16[256,K] @ B16[N,K]^T + bias. (validated)
// ---------------------------------------------------------------------------
__global__ __launch_bounds__(256) void mfma_gemmN(
    const ushort* __restrict__ A16, int K,
    const ushort* __restrict__ B16, const float* __restrict__ bias,
    float* __restrict__ C, int N, ushort* __restrict__ xcast)
{
    int tid = threadIdx.x;
    int lane = tid & 63, wv = tid >> 6;
    int m0 = blockIdx.x * 32;
    int n0 = blockIdx.y * 64;
    int wm = wv >> 1, wn = wv & 1;
    int cl = lane & 15, ko = (lane >> 4) * 8;

    const ushort* ap  = A16 + (size_t)(m0 + wm * 16 + cl) * K + ko;
    const ushort* bp0 = B16 + (size_t)(n0 + wn * 32 + cl) * K + ko;
    const ushort* bp1 = bp0 + (size_t)16 * K;

    f32x4 acc0 = {0.f, 0.f, 0.f, 0.f};
    f32x4 acc1 = {0.f, 0.f, 0.f, 0.f};
    int nks = K >> 5;
#pragma unroll 2
    for (int ks = 0; ks < nks; ++ks) {
        bf16x8 a  = *(const bf16x8*)ap;
        bf16x8 b0 = *(const bf16x8*)bp0;
        bf16x8 b1 = *(const bf16x8*)bp1;
        ap += 32; bp0 += 32; bp1 += 32;
        acc0 = __builtin_amdgcn_mfma_f32_16x16x32_bf16(a, b0, acc0, 0, 0, 0);
        acc1 = __builtin_amdgcn_mfma_f32_16x16x32_bf16(a, b1, acc1, 0, 0, 0);
    }
    int orow = m0 + wm * 16 + (lane >> 4) * 4;
    int ocol = n0 + wn * 32 + cl;
    float bb0 = bias ? bias[ocol] : 0.f;
    float bb1 = bias ? bias[ocol + 16] : 0.f;
#pragma unroll
    for (int r2 = 0; r2 < 4; ++r2) {
        float v0 = acc0[r2] + bb0;
        float v1 = acc1[r2] + bb1;
        C[(size_t)(orow + r2) * N + ocol]      = v0;
        C[(size_t)(orow + r2) * N + ocol + 16] = v1;
        if (xcast) {
            xcast[(size_t)(orow + r2) * 1024 + ocol]      = f2bf(v0);
            xcast[(size_t)(orow + r2) * 1024 + ocol + 16] = f2bf(v1);
        }
    }
}

// ---------------------------------------------------------------------------
// mfma_gemm (LSTM, split-K=2 over grid.z)
// ---------------------------------------------------------------------------
__global__ __launch_bounds__(256) void mfma_gemm(
    const ushort* __restrict__ A16, const ushort* __restrict__ B16,
    float* __restrict__ G0, float* __restrict__ G1)
{
    int tid = threadIdx.x;
    int lane = tid & 63, wv = tid >> 6;
    int m0 = blockIdx.x * 32;
    int n0 = blockIdx.y * 64;
    int kbase = blockIdx.z * 512;
    float* Gout = blockIdx.z ? G1 : G0;
    int wm = wv >> 1, wn = wv & 1;
    int cl = lane & 15, ko = (lane >> 4) * 8;

    const ushort* ap  = A16 + (size_t)(m0 + wm * 16 + cl) * 1024 + kbase + ko;
    const ushort* bp0 = B16 + (size_t)(n0 + wn * 32 + cl) * 1024 + kbase + ko;
    const ushort* bp1 = bp0 + (size_t)16 * 1024;

    f32x4 acc0 = {0.f, 0.f, 0.f, 0.f};
    f32x4 acc1 = {0.f, 0.f, 0.f, 0.f};
#pragma unroll
    for (int ks = 0; ks < 16; ++ks) {
        bf16x8 a  = *(const bf16x8*)(ap  + ks * 32);
        bf16x8 b0 = *(const bf16x8*)(bp0 + ks * 32);
        bf16x8 b1 = *(const bf16x8*)(bp1 + ks * 32);
        acc0 = __builtin_amdgcn_mfma_f32_16x16x32_bf16(a, b0, acc0, 0, 0, 0);
        acc1 = __builtin_amdgcn_mfma_f32_16x16x32_bf16(a, b1, acc1, 0, 0, 0);
    }
    int orow = m0 + wm * 16 + (lane >> 4) * 4;
    int ocol = n0 + wn * 32 + cl;
#pragma unroll
    for (int r2 = 0; r2 < 4; ++r2) {
        Gout[(size_t)(orow + r2) * 2048 + ocol]      = acc0[r2];
        Gout[(size_t)(orow + r2) * 2048 + ocol + 16] = acc1[r2];
    }
}

// ---------------------------------------------------------------------------
// gru_combine
// ---------------------------------------------------------------------------
__global__ __launch_bounds__(256) void gru_combine(
    const float* __restrict__ Cgi, const float* __restrict__ Cgh,
    const float* __restrict__ h_in, float* __restrict__ ah_out,
    ushort* __restrict__ ah16, ushort* __restrict__ Xrnn16)
{
    int b = blockIdx.x, j = threadIdx.x;
    float gir = Cgi[b * 768 + j], giz = Cgi[b * 768 + 256 + j], gin = Cgi[b * 768 + 512 + j];
    float ghr = Cgh[b * 768 + j], ghz = Cgh[b * 768 + 256 + j], ghn = Cgh[b * 768 + 512 + j];
    float rr = fast_sigmoid(gir + ghr);
    float zz = fast_sigmoid(giz + ghz);
    float nn = fast_tanh(gin + rr * ghn);
    float h = (1.f - zz) * nn + zz * h_in[b * 256 + j];
    ah_out[b * 256 + j] = h;
    ah16[b * 256 + j] = f2bf(h);
    Xrnn16[b * 832 + 256 + j] = f2bf(h);
}

// ---------------------------------------------------------------------------
// attn_u v14: softmax_ctx TOPOLOGY — grid(256), block = one batch row b,
// 1024 threads = 16 waves. Internal loop over ten 64-t chunks:
//   conv (weights in VGPRs) -> barrier -> MFMA -> barrier ->
//   contiguous esp stream (wave w reads rows w+16*rr) -> barrier.
// Per-CU memory behavior identical to softmax_ctx's enc stream.
// ---------------------------------------------------------------------------
#define PLP 264
__global__ __launch_bounds__(1024) void attn_u_kernel(
    const float* __restrict__ esp, const float* __restrict__ pq,
    const float* __restrict__ cum, const float* __restrict__ prv,
    const float* __restrict__ conv_w, const ushort* __restrict__ Lw16,
    const float* __restrict__ L_b, const float* __restrict__ v_w,
    float* __restrict__ u)
{
    __shared__ float cumF[672], prvF[672];   // i -> t = i-15 (zero padded)
    __shared__ ushort lwS[8192];
    __shared__ ushort locs[64][40];
    __shared__ ushort plS[64 * PLP];
    __shared__ float pq2s[256], vvs[256];
    int b = blockIdx.x;
    int tid = threadIdx.x;
    int lane = tid & 63, w = tid >> 6;     // 16 waves
    int tt = w & 3, dtg = w >> 2;
    int cl = lane & 15, gr = lane >> 4;
    int f = tid & 31, ts5 = tid >> 5;      // conv role (persistent across chunks)

    // conv weights into registers (once per block)
    float wc[31], wp[31];
#pragma unroll
    for (int k = 0; k < 31; ++k) {
        wc[k] = conv_w[f * 62 + k];
        wp[k] = conv_w[f * 62 + 31 + k];
    }

    // stage: full cum/prv rows (with halo), lwS, pq2s, vvs
    for (int i = tid; i < 672; i += 1024) {
        int tg = i - 15;
        bool ok = (tg >= 0) && (tg < T_);
        cumF[i] = ok ? cum[b * T_ + tg] : 0.f;
        prvF[i] = ok ? prv[b * T_ + tg] : 0.f;
    }
    {
        const float4* src = (const float4*)Lw16;
        float4* dst = (float4*)lwS;
        dst[tid] = src[tid];
    }
    if (tid < 256) {
        pq2s[tid] = pq[b * 256 + tid] + L_b[tid];
        vvs[tid] = v_w[tid];
    }
    __syncthreads();

    float4 pq4 = *(const float4*)&pq2s[lane * 4];
    float4 vv4 = *(const float4*)&vvs[lane * 4];

    for (int ch = 0; ch < 10; ++ch) {
        int t0 = ch * 64;
        // conv: thread (f, ts5) computes local t = ts5 and ts5+32
        {
            float a0 = 0.f, a1 = 0.f;
#pragma unroll
            for (int k = 0; k < 31; ++k) {
                a0 = fmaf(cumF[t0 + ts5 + k], wc[k], fmaf(prvF[t0 + ts5 + k], wp[k], a0));
                a1 = fmaf(cumF[t0 + ts5 + 32 + k], wc[k], fmaf(prvF[t0 + ts5 + 32 + k], wp[k], a1));
            }
            locs[ts5][f] = f2bf(a0);
            locs[ts5 + 32][f] = f2bf(a1);
        }
        __syncthreads();
        // MFMA: wave (tt,dtg) -> pl[t in tile tt][d group dtg] into plS
        {
            bf16x8 locf = *(const bf16x8*)&locs[tt * 16 + cl][gr * 8];
#pragma unroll
            for (int j = 0; j < 4; ++j) {
                int dt = dtg * 4 + j;
                bf16x8 af = *(const bf16x8*)&lwS[(dt * 64 + lane) * 8];
                f32x4 acc = {0.f, 0.f, 0.f, 0.f};
                acc = __builtin_amdgcn_mfma_f32_16x16x32_bf16(af, locf, acc, 0, 0, 0);
                ushort4 pk;
                pk.x = f2bf(acc[0]); pk.y = f2bf(acc[1]);
                pk.z = f2bf(acc[2]); pk.w = f2bf(acc[3]);
                *(ushort4*)&plS[(tt * 16 + cl) * PLP + dt * 16 + gr * 4] = pk;
            }
        }
        __syncthreads();
        // esp stream: wave w handles rows w, w+16, w+32, w+48 (contiguous 1KB)
#pragma unroll
        for (int rr = 0; rr < 4; ++rr) {
            int row = w + rr * 16;
            int tg = t0 + row;
            int tc = (tg < T_) ? tg : (T_ - 1);
            float4 e4 = *((const float4*)(esp + ((size_t)b * T_ + tc) * 256) + lane);
            ushort4 pl4 = *(const ushort4*)&plS[row * PLP + lane * 4];
            float s = 0.f;
            s = fmaf(fast_tanh(e4.x + pq4.x + bf2f(pl4.x)), vv4.x, s);
            s = fmaf(fast_tanh(e4.y + pq4.y + bf2f(pl4.y)), vv4.y, s);
            s = fmaf(fast_tanh(e4.z + pq4.z + bf2f(pl4.z)), vv4.z, s);
            s = fmaf(fast_tanh(e4.w + pq4.w + bf2f(pl4.w)), vv4.w, s);
#pragma unroll
            for (int off = 32; off > 0; off >>= 1) s += __shfl_xor(s, off, 64);
            if (lane == 0 && tg < T_) u[b * T_ + tg] = s;
        }
        __syncthreads();
    }
}

// ---------------------------------------------------------------------------
// softmax + context (ctx also written bf16 into Xrnn16)
// ---------------------------------------------------------------------------
__global__ __launch_bounds__(1024) void softmax_ctx_kernel(
    const float* __restrict__ u, const int* __restrict__ plen,
    const float* __restrict__ enc,
    float* __restrict__ scores, float* __restrict__ ctx_out,
    ushort* __restrict__ Xrnn16)
{
    __shared__ float sc[T_];
    __shared__ float red[16];
    __shared__ float part[16][256];
    int b = blockIdx.x, tid = threadIdx.x;
    int lane = tid & 63, wid = tid >> 6;
    int pl = plen[b];
    float mv = -1e30f;
    if (tid < T_) {
        float uv = u[b * T_ + tid];
        mv = (tid < pl) ? uv : -1e9f;
        sc[tid] = mv;
    }
    float m = mv;
#pragma unroll
    for (int off = 32; off > 0; off >>= 1) m = fmaxf(m, __shfl_xor(m, off, 64));
    if (lane == 0) red[wid] = m;
    __syncthreads();
    m = red[0];
#pragma unroll
    for (int i = 1; i < 16; ++i) m = fmaxf(m, red[i]);
    float ev = 0.f;
    if (tid < T_) ev = __expf(sc[tid] - m);
    float s = ev;
    __syncthreads();
#pragma unroll
    for (int off = 32; off > 0; off >>= 1) s += __shfl_xor(s, off, 64);
    if (lane == 0) red[wid] = s;
    __syncthreads();
    float tot = 0.f;
#pragma unroll
    for (int i = 0; i < 16; ++i) tot += red[i];
    float inv = __fdividef(1.0f, tot);
    if (tid < T_) {
        float scv = ev * inv;
        scores[b * T_ + tid] = scv;
        sc[tid] = scv;
    }
    __syncthreads();
    float a0 = 0.f, a1 = 0.f, a2 = 0.f, a3 = 0.f;
    const float4* ep = (const float4*)(enc + ((size_t)b * T_ + wid) * 256) + lane;
    for (int t = wid; t < T_; t += 16) {
        float sv = sc[t];
        float4 ev4 = *ep;
        a0 = fmaf(sv, ev4.x, a0);
        a1 = fmaf(sv, ev4.y, a1);
        a2 = fmaf(sv, ev4.z, a2);
        a3 = fmaf(sv, ev4.w, a3);
        ep += 16 * 64;
    }
    part[wid][lane * 4 + 0] = a0;
    part[wid][lane * 4 + 1] = a1;
    part[wid][lane * 4 + 2] = a2;
    part[wid][lane * 4 + 3] = a3;
    __syncthreads();
    if (tid < 256) {
        float c = 0.f;
#pragma unroll
        for (int q = 0; q < 16; ++q) c += part[q][tid];
        ctx_out[b * 256 + tid] = c;
        Xrnn16[b * 832 + tid] = f2bf(c);
    }
}

// ---------------------------------------------------------------------------
// lstm_combine2
// ---------------------------------------------------------------------------
__global__ __launch_bounds__(512) void lstm_combine2(
    const float* __restrict__ G0, const float* __restrict__ G1,
    const float* __restrict__ bih, const float* __restrict__ bhh,
    const float* __restrict__ c_in, const float* __restrict__ x_in,
    float* __restrict__ h_out, float* __restrict__ c_out,
    float* __restrict__ x_next,
    const float* __restrict__ h_next_in, ushort* __restrict__ xh_next)
{
    int b = blockIdx.x, j = threadIdx.x;
    size_t base = (size_t)b * 2048;
    float gi = G0[base + j] + G1[base + j] + bih[j] + bhh[j];
    float gf = G0[base + 512 + j] + G1[base + 512 + j] + bih[512 + j] + bhh[512 + j];
    float gg = G0[base + 1024 + j] + G1[base + 1024 + j] + bih[1024 + j] + bhh[1024 + j];
    float go = G0[base + 1536 + j] + G1[base + 1536 + j] + bih[1536 + j] + bhh[1536 + j];
    float c = fast_sigmoid(gf) * c_in[b * 512 + j] + fast_sigmoid(gi) * fast_tanh(gg);
    float h = fast_sigmoid(go) * fast_tanh(c);
    float xn = x_in[b * 512 + j] + h;
    h_out[b * 512 + j] = h;
    c_out[b * 512 + j] = c;
    x_next[b * 512 + j] = xn;
    if (xh_next) {
        xh_next[(size_t)b * 1024 + j] = f2bf(xn);
        xh_next[(size_t)b * 1024 + 512 + j] = f2bf(h_next_in[b * 512 + j]);
    }
}

// ---------------------------------------------------------------------------
// mel
// ---------------------------------------------------------------------------
__global__ __launch_bounds__(256) void mel_kernel(
    const float* __restrict__ x2, const float* __restrict__ mel_w,
    int r, float* __restrict__ mels)
{
    __shared__ float xl[512];
    int b = blockIdx.x, tid = threadIdx.x;
    xl[tid] = x2[b * 512 + tid];
    xl[256 + tid] = x2[b * 512 + 256 + tid];
    __syncthreads();
    for (int idx = tid; idx < 80 * r; idx += 256) {
        int mrow = (idx / r) * 10 + (idx % r);
        const float4* w = (const float4*)(mel_w + (size_t)mrow * 512);
        const float4* xv = (const float4*)xl;
        float acc = 0.f;
#pragma unroll 16
        for (int k = 0; k < 128; ++k) {
            float4 a = w[k], c = xv[k];
            acc += a.x * c.x + a.y * c.y + a.z * c.z + a.w * c.w;
        }
        mels[(size_t)b * 80 * r + idx] = acc;
    }
}

// ---------------------------------------------------------------------------
extern "C" void kernel_launch(void* const* d_in, const int* in_sizes, int n_in,
                              void* d_out, int out_size, void* d_ws, size_t ws_size,
                              hipStream_t stream)
{
    const float* enc    = (const float*)d_in[0];
    const float* esp    = (const float*)d_in[1];
    const float* pre_in = (const float*)d_in[2];
    const float* ah_in  = (const float*)d_in[3];
    const float* h1_in  = (const float*)d_in[4];
    const float* h2_in  = (const float*)d_in[5];
    const float* c1_in  = (const float*)d_in[6];
    const float* c2_in  = (const float*)d_in[7];
    const float* ctx_in = (const float*)d_in[8];
    const float* spk    = (const float*)d_in[9];
    const float* noise  = (const float*)d_in[10];
    const float* cum    = (const float*)d_in[11];
    const float* prv    = (const float*)d_in[12];
    const int*   plen   = (const int*)d_in[13];
    const float* fc1_w  = (const float*)d_in[14];
    const float* fc1_b  = (const float*)d_in[15];
    const float* fc2_w  = (const float*)d_in[16];
    const float* fc2_b  = (const float*)d_in[17];
    const float* conv_w = (const float*)d_in[18];
    const float* L_w    = (const float*)d_in[19];
    const float* L_b    = (const float*)d_in[20];
    const float* W_w    = (const float*)d_in[21];
    const float* W_b    = (const float*)d_in[22];
    const float* v_w    = (const float*)d_in[23];
    const float* g_wih  = (const float*)d_in[24];
    const float* g_whh  = (const float*)d_in[25];
    const float* g_bih  = (const float*)d_in[26];
    const float* g_bhh  = (const float*)d_in[27];
    const float* ri_w   = (const float*)d_in[28];
    const float* ri_b   = (const float*)d_in[29];
    const float* l1_wih = (const float*)d_in[30];
    const float* l1_whh = (const float*)d_in[31];
    const float* l1_bih = (const float*)d_in[32];
    const float* l1_bhh = (const float*)d_in[33];
    const float* l2_wih = (const float*)d_in[34];
    const float* l2_whh = (const float*)d_in[35];
    const float* l2_bih = (const float*)d_in[36];
    const float* l2_bhh = (const float*)d_in[37];
    const float* mel_w  = (const float*)d_in[38];

    int r = (out_size - 808960) / 20480;
    if (r < 1) r = 1;
    if (r > 10) r = 10;

    float* out    = (float*)d_out;
    float* mels   = out;
    float* scores = out + (size_t)20480 * r;
    float* ah_out = scores + 153600;
    float* h1_out = ah_out + 65536;
    float* h2_out = h1_out + 131072;
    float* c1_out = h2_out + 131072;
    float* c2_out = c1_out + 131072;
    float* ctx_out = c2_out + 131072;

    float* ws   = (float*)d_ws;
    float* Cgi  = ws;                      // 256*768
    float* Cgh  = Cgi + 196608;            // 256*768
    float* pq   = Cgh + 196608;            // 256*256
    float* uu   = pq + 65536;              // 256*600
    float* x0   = uu + 153600;             // 256*512
    float* x1   = x0 + 131072;
    float* x2   = x1 + 131072;
    float* G0   = x2 + 131072;             // 256*2048
    float* G1   = G0 + 524288;             // 256*2048
    ushort* Lw16   = (ushort*)(G1 + 524288);  // 8192
    ushort* Xgru16 = Lw16 + 8192;             // 256*640
    ushort* Xrnn16 = Xgru16 + 163840;         // 256*832
    ushort* ah16   = Xrnn16 + 212992;         // 256*256
    ushort* ahin16 = ah16 + 65536;            // 256*256
    ushort* wcat1  = ahin16 + 65536;          // 2048*1024
    ushort* wcat2  = wcat1 + 2097152;         // 2048*1024
    ushort* gwih16 = wcat2 + 2097152;         // 768*640
    ushort* gwhh16 = gwih16 + 491520;         // 768*256
    ushort* Ww16   = gwhh16 + 196608;         // 256*256
    ushort* riw16  = Ww16 + 65536;            // 512*832
    ushort* xh1    = riw16 + 425984;          // 256*1024
    ushort* xh2    = xh1 + 262144;            // 256*1024

    prenet_kernel<<<256, 256, 0, stream>>>(pre_in, noise, fc1_w, fc1_b, fc2_w, fc2_b,
                                           ctx_in, spk, L_w, Lw16, Xgru16, Xrnn16);
    convert_all<<<5440, 256, 0, stream>>>(l1_wih, l1_whh, l2_wih, l2_whh,
                                          g_wih, g_whh, W_w, ri_w, ah_in, h1_in,
                                          wcat1, wcat2, gwih16, gwhh16,
                                          Ww16, riw16, ahin16, xh1);
    mfma_gemmN<<<dim3(8, 12), 256, 0, stream>>>(Xgru16, 640, gwih16, g_bih, Cgi, 768, nullptr);
    mfma_gemmN<<<dim3(8, 12), 256, 0, stream>>>(ahin16, 256, gwhh16, g_bhh, Cgh, 768, nullptr);
    gru_combine<<<256, 256, 0, stream>>>(Cgi, Cgh, ah_in, ah_out, ah16, Xrnn16);
    mfma_gemmN<<<dim3(8, 4), 256, 0, stream>>>(ah16, 256, Ww16, W_b, pq, 256, nullptr);
    attn_u_kernel<<<256, 1024, 0, stream>>>(esp, pq, cum, prv, conv_w, Lw16, L_b, v_w, uu);
    softmax_ctx_kernel<<<256, 1024, 0, stream>>>(uu, plen, enc, scores, ctx_out, Xrnn16);
    mfma_gemmN<<<dim3(8, 8), 256, 0, stream>>>(Xrnn16, 832, riw16, ri_b, x0, 512, xh1);
    mfma_gemm<<<dim3(8, 32, 2), 256, 0, stream>>>(xh1, wcat1, G0, G1);
    lstm_combine2<<<256, 512, 0, stream>>>(G0, G1, l1_bih, l1_bhh, c1_in, x0,
                                           h1_out, c1_out, x1, h2_in, xh2);
    mfma_gemm<<<dim3(8, 32, 2), 256, 0, stream>>>(xh2, wcat2, G0, G1);
    lstm_combine2<<<256, 512, 0, stream>>>(G0, G1, l2_bih, l2_bhh, c2_in, x1,
                                           h2_out, c2_out, x2, nullptr, nullptr);
    mel_kernel<<<256, 256, 0, stream>>>(x2, mel_w, r, mels);
}

// Round 20
// 187.916 us; speedup vs baseline: 1.1774x; 1.1774x over previous
//
#include <hip/hip_runtime.h>
#include <hip/hip_bf16.h>
#include <cstdint>

#define B_ 256
#define T_ 600
#define D_ 256

typedef __attribute__((ext_vector_type(8))) short bf16x8;
typedef __attribute__((ext_vector_type(4))) float f32x4;

__device__ __forceinline__ float fast_sigmoid(float x) {
    return __fdividef(1.0f, 1.0f + __expf(-x));
}
__device__ __forceinline__ float fast_tanh(float x) {
    return 1.0f - __fdividef(2.0f, __expf(2.0f * x) + 1.0f);
}
__device__ __forceinline__ ushort f2bf(float f) {
    unsigned u = __float_as_uint(f);
    u += 0x7FFF + ((u >> 16) & 1);   // round-to-nearest-even
    return (ushort)(u >> 16);
}

// ---------------------------------------------------------------------------
// prenet: init_concat (bf16 Xgru16 / Xrnn16 parts) + prenet MLP + Lw16 pack
// ---------------------------------------------------------------------------
__global__ __launch_bounds__(256) void prenet_kernel(
    const float* __restrict__ pre_in, const float* __restrict__ noise,
    const float* __restrict__ w1, const float* __restrict__ b1,
    const float* __restrict__ w2, const float* __restrict__ b2,
    const float* __restrict__ ctx_in, const float* __restrict__ spk,
    const float* __restrict__ L_w, ushort* __restrict__ Lw16,
    ushort* __restrict__ Xgru16, ushort* __restrict__ Xrnn16)
{
    __shared__ float xin[144];
    __shared__ float p1[256];
    int b = blockIdx.x, t = threadIdx.x;
    if (b == 0) {
        for (int o = t; o < 8192; o += 256) {
            int dt = o >> 9;
            int ln = (o >> 3) & 63;
            int j  = o & 7;
            int in_idx = (dt * 16 + (ln & 15)) * 32 + (ln >> 4) * 8 + j;
            Lw16[o] = f2bf(L_w[in_idx]);
        }
    }
    float s = spk[b * 256 + t];
    Xgru16[b * 640 + t] = f2bf(ctx_in[b * 256 + t]);
    Xgru16[b * 640 + 384 + t] = f2bf(s);
    Xrnn16[b * 832 + 512 + t] = f2bf(s);
    if (t < 64) Xrnn16[b * 832 + 768 + t] = f2bf(noise[b * 64 + t]);
    if (t < 80) xin[t] = pre_in[b * 80 + t];
    else if (t < 144) xin[t] = noise[b * 64 + (t - 80)];
    __syncthreads();
    float acc = b1[t];
    const float4* w = (const float4*)(w1 + t * 144);
    const float4* xi = (const float4*)xin;
#pragma unroll 9
    for (int k = 0; k < 36; ++k) {
        float4 wv = w[k]; float4 xv = xi[k];
        acc += wv.x * xv.x + wv.y * xv.y + wv.z * xv.z + wv.w * xv.w;
    }
    p1[t] = fmaxf(acc, 0.f);
    __syncthreads();
    if (t < 128) {
        float a2 = b2[t];
        const float4* w2v = (const float4*)(w2 + t * 256);
        const float4* pv = (const float4*)p1;
#pragma unroll 8
        for (int k = 0; k < 64; ++k) {
            float4 wv = w2v[k]; float4 xv = pv[k];
            a2 += wv.x * xv.x + wv.y * xv.y + wv.z * xv.z + wv.w * xv.w;
        }
        Xgru16[b * 640 + 256 + t] = f2bf(fmaxf(a2, 0.f));
    }
}

// ---------------------------------------------------------------------------
// convert_all: every weight/input cast to bf16 in one launch.
// ---------------------------------------------------------------------------
__global__ __launch_bounds__(256) void convert_all(
    const float* __restrict__ w1ih, const float* __restrict__ w1hh,
    const float* __restrict__ w2ih, const float* __restrict__ w2hh,
    const float* __restrict__ gwih, const float* __restrict__ gwhh,
    const float* __restrict__ Ww, const float* __restrict__ riw,
    const float* __restrict__ ahin, const float* __restrict__ h1in,
    ushort* __restrict__ wcat1, ushort* __restrict__ wcat2,
    ushort* __restrict__ gwih16, ushort* __restrict__ gwhh16,
    ushort* __restrict__ Ww16, ushort* __restrict__ riw16,
    ushort* __restrict__ ahin16, ushort* __restrict__ xh1)
{
    int bid = blockIdx.x, t = threadIdx.x;
    if (bid < 4096) {
        int n = bid & 2047;
        int layer = bid >> 11;
        const float* wih = layer ? w2ih : w1ih;
        const float* whh = layer ? w2hh : w1hh;
        ushort* dst = layer ? wcat2 : wcat1;
        const float* src = (t < 128) ? (wih + (size_t)n * 512 + t * 4)
                                     : (whh + (size_t)n * 512 + (t - 128) * 4);
        float4 v = *(const float4*)src;
        ushort4 o;
        o.x = f2bf(v.x); o.y = f2bf(v.y); o.z = f2bf(v.z); o.w = f2bf(v.w);
        *(ushort4*)&dst[(size_t)n * 1024 + t * 4] = o;
        return;
    }
    bid -= 4096;
    if (bid >= 1216) {           // h1_in -> xh1[:,512:1024)
        bid -= 1216;
        size_t i = (size_t)bid * 1024 + t * 4;
        float4 v = *(const float4*)&h1in[i];
        int b = (int)(i >> 9), k = (int)(i & 511);
        ushort4 o;
        o.x = f2bf(v.x); o.y = f2bf(v.y); o.z = f2bf(v.z); o.w = f2bf(v.w);
        *(ushort4*)&xh1[(size_t)b * 1024 + 512 + k] = o;
        return;
    }
    const float* src; ushort* dst;
    if (bid < 480)       { src = gwih; dst = gwih16; }
    else if (bid < 672)  { bid -= 480;  src = gwhh; dst = gwhh16; }
    else if (bid < 736)  { bid -= 672;  src = Ww;   dst = Ww16; }
    else if (bid < 1152) { bid -= 736;  src = riw;  dst = riw16; }
    else                 { bid -= 1152; src = ahin; dst = ahin16; }
    size_t i = (size_t)bid * 1024 + t * 4;
    float4 v = *(const float4*)&src[i];
    ushort4 o;
    o.x = f2bf(v.x); o.y = f2bf(v.y); o.z = f2bf(v.z); o.w = f2bf(v.w);
    *(ushort4*)&dst[i] = o;
}

// ---------------------------------------------------------------------------
// mfma_gemmN: C[256,N] = A16[256,K] @ B16[N,K]^T + bias. (validated)
// ---------------------------------------------------------------------------
__global__ __launch_bounds__(256) void mfma_gemmN(
    const ushort* __restrict__ A16, int K,
    const ushort* __restrict__ B16, const float* __restrict__ bias,
    float* __restrict__ C, int N, ushort* __restrict__ xcast)
{
    int tid = threadIdx.x;
    int lane = tid & 63, wv = tid >> 6;
    int m0 = blockIdx.x * 32;
    int n0 = blockIdx.y * 64;
    int wm = wv >> 1, wn = wv & 1;
    int cl = lane & 15, ko = (lane >> 4) * 8;

    const ushort* ap  = A16 + (size_t)(m0 + wm * 16 + cl) * K + ko;
    const ushort* bp0 = B16 + (size_t)(n0 + wn * 32 + cl) * K + ko;
    const ushort* bp1 = bp0 + (size_t)16 * K;

    f32x4 acc0 = {0.f, 0.f, 0.f, 0.f};
    f32x4 acc1 = {0.f, 0.f, 0.f, 0.f};
    int nks = K >> 5;
#pragma unroll 2
    for (int ks = 0; ks < nks; ++ks) {
        bf16x8 a  = *(const bf16x8*)ap;
        bf16x8 b0 = *(const bf16x8*)bp0;
        bf16x8 b1 = *(const bf16x8*)bp1;
        ap += 32; bp0 += 32; bp1 += 32;
        acc0 = __builtin_amdgcn_mfma_f32_16x16x32_bf16(a, b0, acc0, 0, 0, 0);
        acc1 = __builtin_amdgcn_mfma_f32_16x16x32_bf16(a, b1, acc1, 0, 0, 0);
    }
    int orow = m0 + wm * 16 + (lane >> 4) * 4;
    int ocol = n0 + wn * 32 + cl;
    float bb0 = bias ? bias[ocol] : 0.f;
    float bb1 = bias ? bias[ocol + 16] : 0.f;
#pragma unroll
    for (int r2 = 0; r2 < 4; ++r2) {
        float v0 = acc0[r2] + bb0;
        float v1 = acc1[r2] + bb1;
        C[(size_t)(orow + r2) * N + ocol]      = v0;
        C[(size_t)(orow + r2) * N + ocol + 16] = v1;
        if (xcast) {
            xcast[(size_t)(orow + r2) * 1024 + ocol]      = f2bf(v0);
            xcast[(size_t)(orow + r2) * 1024 + ocol + 16] = f2bf(v1);
        }
    }
}

// ---------------------------------------------------------------------------
// mfma_gemm (LSTM, split-K=2 over grid.z)
// ---------------------------------------------------------------------------
__global__ __launch_bounds__(256) void mfma_gemm(
    const ushort* __restrict__ A16, const ushort* __restrict__ B16,
    float* __restrict__ G0, float* __restrict__ G1)
{
    int tid = threadIdx.x;
    int lane = tid & 63, wv = tid >> 6;
    int m0 = blockIdx.x * 32;
    int n0 = blockIdx.y * 64;
    int kbase = blockIdx.z * 512;
    float* Gout = blockIdx.z ? G1 : G0;
    int wm = wv >> 1, wn = wv & 1;
    int cl = lane & 15, ko = (lane >> 4) * 8;

    const ushort* ap  = A16 + (size_t)(m0 + wm * 16 + cl) * 1024 + kbase + ko;
    const ushort* bp0 = B16 + (size_t)(n0 + wn * 32 + cl) * 1024 + kbase + ko;
    const ushort* bp1 = bp0 + (size_t)16 * 1024;

    f32x4 acc0 = {0.f, 0.f, 0.f, 0.f};
    f32x4 acc1 = {0.f, 0.f, 0.f, 0.f};
#pragma unroll
    for (int ks = 0; ks < 16; ++ks) {
        bf16x8 a  = *(const bf16x8*)(ap  + ks * 32);
        bf16x8 b0 = *(const bf16x8*)(bp0 + ks * 32);
        bf16x8 b1 = *(const bf16x8*)(bp1 + ks * 32);
        acc0 = __builtin_amdgcn_mfma_f32_16x16x32_bf16(a, b0, acc0, 0, 0, 0);
        acc1 = __builtin_amdgcn_mfma_f32_16x16x32_bf16(a, b1, acc1, 0, 0, 0);
    }
    int orow = m0 + wm * 16 + (lane >> 4) * 4;
    int ocol = n0 + wn * 32 + cl;
#pragma unroll
    for (int r2 = 0; r2 < 4; ++r2) {
        Gout[(size_t)(orow + r2) * 2048 + ocol]      = acc0[r2];
        Gout[(size_t)(orow + r2) * 2048 + ocol + 16] = acc1[r2];
    }
}

// ---------------------------------------------------------------------------
// gru_combine: gates -> ah_out (fp32 output) + ah16 + Xrnn16 mid section
// ---------------------------------------------------------------------------
__global__ __launch_bounds__(256) void gru_combine(
    const float* __restrict__ Cgi, const float* __restrict__ Cgh,
    const float* __restrict__ h_in, float* __restrict__ ah_out,
    ushort* __restrict__ ah16, ushort* __restrict__ Xrnn16)
{
    int b = blockIdx.x, j = threadIdx.x;
    float gir = Cgi[b * 768 + j], giz = Cgi[b * 768 + 256 + j], gin = Cgi[b * 768 + 512 + j];
    float ghr = Cgh[b * 768 + j], ghz = Cgh[b * 768 + 256 + j], ghn = Cgh[b * 768 + 512 + j];
    float rr = fast_sigmoid(gir + ghr);
    float zz = fast_sigmoid(giz + ghz);
    float nn = fast_tanh(gin + rr * ghn);
    float h = (1.f - zz) * nn + zz * h_in[b * 256 + j];
    ah_out[b * 256 + j] = h;
    ah16[b * 256 + j] = f2bf(h);
    Xrnn16[b * 832 + 256 + j] = f2bf(h);
}

// ---------------------------------------------------------------------------
// attn_u v10 (best measured): scalar esp preload + partial barrier + MFMA.
// grid (10, B), 256 threads = 4 waves x 16 t.
// ---------------------------------------------------------------------------
#define TCH 64
__global__ __launch_bounds__(256) void attn_u_kernel(
    const float* __restrict__ esp, const float* __restrict__ pq,
    const float* __restrict__ cum, const float* __restrict__ prv,
    const float* __restrict__ conv_w, const ushort* __restrict__ Lw16,
    const float* __restrict__ L_b, const float* __restrict__ v_w,
    float* __restrict__ u)
{
    __shared__ float cumL[TCH + 32], prvL[TCH + 32];
    __shared__ float cwL[32 * 62];
    __shared__ ushort lwS[8192];
    __shared__ ushort locs[TCH][40];
    __shared__ float pq2s[256], vvs[256];
    int b = blockIdx.y;
    int t0 = blockIdx.x * TCH;
    int tid = threadIdx.x;
    int lane = tid & 63, wv = tid >> 6;
    int cl = lane & 15, gr = lane >> 4;

    for (int i = tid; i < TCH + 30; i += 256) {
        int tg = t0 + i - 15;
        bool ok = (tg >= 0) && (tg < T_);
        cumL[i] = ok ? cum[b * T_ + tg] : 0.f;
        prvL[i] = ok ? prv[b * T_ + tg] : 0.f;
    }
    for (int i = tid; i < 32 * 62; i += 256) cwL[i] = conv_w[i];
    {
        const float4* src = (const float4*)Lw16;
        float4* dst = (float4*)lwS;
#pragma unroll
        for (int i = 0; i < 4; ++i) dst[tid + i * 256] = src[tid + i * 256];
    }
    pq2s[tid] = pq[b * 256 + tid] + L_b[tid];
    vvs[tid] = v_w[tid];

    int tw = t0 + wv * 16 + cl;
    int tc = (tw < T_) ? tw : (T_ - 1);
    const float4* ep4 = (const float4*)(esp + ((size_t)b * T_ + tc) * 256) + gr;
    float e[64];
#pragma unroll
    for (int dt = 0; dt < 16; ++dt) {
        float4 t4 = ep4[dt * 4];
        e[dt * 4 + 0] = t4.x; e[dt * 4 + 1] = t4.y;
        e[dt * 4 + 2] = t4.z; e[dt * 4 + 3] = t4.w;
    }

    asm volatile("s_waitcnt lgkmcnt(0)" ::: "memory");
    __builtin_amdgcn_s_barrier();
    __builtin_amdgcn_sched_barrier(0);

    {
        int f = tid & 31, ts = tid >> 5;
        const float* c0 = &cwL[f * 62];
        float acc[8] = {};
#pragma unroll
        for (int k = 0; k < 31; ++k) {
            float wcv = c0[k], wpv = c0[31 + k];
#pragma unroll
            for (int i = 0; i < 8; ++i)
                acc[i] = fmaf(cumL[ts * 8 + i + k], wcv, fmaf(prvL[ts * 8 + i + k], wpv, acc[i]));
        }
#pragma unroll
        for (int i = 0; i < 8; ++i)
            locs[ts * 8 + i][f] = f2bf(acc[i]);
    }
    __syncthreads();

    bf16x8 locf = *(const bf16x8*)&locs[wv * 16 + cl][gr * 8];
    float sum = 0.f;
#pragma unroll
    for (int dt = 0; dt < 16; ++dt) {
        bf16x8 af = *(const bf16x8*)&lwS[(dt * 64 + lane) * 8];
        float4 pq4 = *(const float4*)&pq2s[dt * 16 + gr * 4];
        float4 vv4 = *(const float4*)&vvs[dt * 16 + gr * 4];
        f32x4 acc = {pq4.x, pq4.y, pq4.z, pq4.w};
        acc = __builtin_amdgcn_mfma_f32_16x16x32_bf16(af, locf, acc, 0, 0, 0);
        sum = fmaf(fast_tanh(e[dt * 4 + 0] + acc[0]), vv4.x, sum);
        sum = fmaf(fast_tanh(e[dt * 4 + 1] + acc[1]), vv4.y, sum);
        sum = fmaf(fast_tanh(e[dt * 4 + 2] + acc[2]), vv4.z, sum);
        sum = fmaf(fast_tanh(e[dt * 4 + 3] + acc[3]), vv4.w, sum);
    }
    sum += __shfl_xor(sum, 16, 64);
    sum += __shfl_xor(sum, 32, 64);
    if (lane < 16 && tw < T_) u[b * T_ + tw] = sum;
}

// ---------------------------------------------------------------------------
// softmax + context (ctx also written bf16 into Xrnn16)
// ---------------------------------------------------------------------------
__global__ __launch_bounds__(1024) void softmax_ctx_kernel(
    const float* __restrict__ u, const int* __restrict__ plen,
    const float* __restrict__ enc,
    float* __restrict__ scores, float* __restrict__ ctx_out,
    ushort* __restrict__ Xrnn16)
{
    __shared__ float sc[T_];
    __shared__ float red[16];
    __shared__ float part[16][256];
    int b = blockIdx.x, tid = threadIdx.x;
    int lane = tid & 63, wid = tid >> 6;
    int pl = plen[b];
    float mv = -1e30f;
    if (tid < T_) {
        float uv = u[b * T_ + tid];
        mv = (tid < pl) ? uv : -1e9f;
        sc[tid] = mv;
    }
    float m = mv;
#pragma unroll
    for (int off = 32; off > 0; off >>= 1) m = fmaxf(m, __shfl_xor(m, off, 64));
    if (lane == 0) red[wid] = m;
    __syncthreads();
    m = red[0];
#pragma unroll
    for (int i = 1; i < 16; ++i) m = fmaxf(m, red[i]);
    float ev = 0.f;
    if (tid < T_) ev = __expf(sc[tid] - m);
    float s = ev;
    __syncthreads();
#pragma unroll
    for (int off = 32; off > 0; off >>= 1) s += __shfl_xor(s, off, 64);
    if (lane == 0) red[wid] = s;
    __syncthreads();
    float tot = 0.f;
#pragma unroll
    for (int i = 0; i < 16; ++i) tot += red[i];
    float inv = __fdividef(1.0f, tot);
    if (tid < T_) {
        float scv = ev * inv;
        scores[b * T_ + tid] = scv;
        sc[tid] = scv;
    }
    __syncthreads();
    float a0 = 0.f, a1 = 0.f, a2 = 0.f, a3 = 0.f;
    const float4* ep = (const float4*)(enc + ((size_t)b * T_ + wid) * 256) + lane;
    for (int t = wid; t < T_; t += 16) {
        float sv = sc[t];
        float4 ev4 = *ep;
        a0 = fmaf(sv, ev4.x, a0);
        a1 = fmaf(sv, ev4.y, a1);
        a2 = fmaf(sv, ev4.z, a2);
        a3 = fmaf(sv, ev4.w, a3);
        ep += 16 * 64;
    }
    part[wid][lane * 4 + 0] = a0;
    part[wid][lane * 4 + 1] = a1;
    part[wid][lane * 4 + 2] = a2;
    part[wid][lane * 4 + 3] = a3;
    __syncthreads();
    if (tid < 256) {
        float c = 0.f;
#pragma unroll
        for (int q = 0; q < 16; ++q) c += part[q][tid];
        ctx_out[b * 256 + tid] = c;
        Xrnn16[b * 832 + tid] = f2bf(c);
    }
}

// ---------------------------------------------------------------------------
// lstm_combine2: gates = G0+G1+bih+bhh; h,c,x_next; optional xh_next pack
// ---------------------------------------------------------------------------
__global__ __launch_bounds__(512) void lstm_combine2(
    const float* __restrict__ G0, const float* __restrict__ G1,
    const float* __restrict__ bih, const float* __restrict__ bhh,
    const float* __restrict__ c_in, const float* __restrict__ x_in,
    float* __restrict__ h_out, float* __restrict__ c_out,
    float* __restrict__ x_next,
    const float* __restrict__ h_next_in, ushort* __restrict__ xh_next)
{
    int b = blockIdx.x, j = threadIdx.x;
    size_t base = (size_t)b * 2048;
    float gi = G0[base + j] + G1[base + j] + bih[j] + bhh[j];
    float gf = G0[base + 512 + j] + G1[base + 512 + j] + bih[512 + j] + bhh[512 + j];
    float gg = G0[base + 1024 + j] + G1[base + 1024 + j] + bih[1024 + j] + bhh[1024 + j];
    float go = G0[base + 1536 + j] + G1[base + 1536 + j] + bih[1536 + j] + bhh[1536 + j];
    float c = fast_sigmoid(gf) * c_in[b * 512 + j] + fast_sigmoid(gi) * fast_tanh(gg);
    float h = fast_sigmoid(go) * fast_tanh(c);
    float xn = x_in[b * 512 + j] + h;
    h_out[b * 512 + j] = h;
    c_out[b * 512 + j] = c;
    x_next[b * 512 + j] = xn;
    if (xh_next) {
        xh_next[(size_t)b * 1024 + j] = f2bf(xn);
        xh_next[(size_t)b * 1024 + 512 + j] = f2bf(h_next_in[b * 512 + j]);
    }
}

// ---------------------------------------------------------------------------
// mel
// ---------------------------------------------------------------------------
__global__ __launch_bounds__(256) void mel_kernel(
    const float* __restrict__ x2, const float* __restrict__ mel_w,
    int r, float* __restrict__ mels)
{
    __shared__ float xl[512];
    int b = blockIdx.x, tid = threadIdx.x;
    xl[tid] = x2[b * 512 + tid];
    xl[256 + tid] = x2[b * 512 + 256 + tid];
    __syncthreads();
    for (int idx = tid; idx < 80 * r; idx += 256) {
        int mrow = (idx / r) * 10 + (idx % r);
        const float4* w = (const float4*)(mel_w + (size_t)mrow * 512);
        const float4* xv = (const float4*)xl;
        float acc = 0.f;
#pragma unroll 16
        for (int k = 0; k < 128; ++k) {
            float4 a = w[k], c = xv[k];
            acc += a.x * c.x + a.y * c.y + a.z * c.z + a.w * c.w;
        }
        mels[(size_t)b * 80 * r + idx] = acc;
    }
}

// ---------------------------------------------------------------------------
extern "C" void kernel_launch(void* const* d_in, const int* in_sizes, int n_in,
                              void* d_out, int out_size, void* d_ws, size_t ws_size,
                              hipStream_t stream)
{
    const float* enc    = (const float*)d_in[0];
    const float* esp    = (const float*)d_in[1];
    const float* pre_in = (const float*)d_in[2];
    const float* ah_in  = (const float*)d_in[3];
    const float* h1_in  = (const float*)d_in[4];
    const float* h2_in  = (const float*)d_in[5];
    const float* c1_in  = (const float*)d_in[6];
    const float* c2_in  = (const float*)d_in[7];
    const float* ctx_in = (const float*)d_in[8];
    const float* spk    = (const float*)d_in[9];
    const float* noise  = (const float*)d_in[10];
    const float* cum    = (const float*)d_in[11];
    const float* prv    = (const float*)d_in[12];
    const int*   plen   = (const int*)d_in[13];
    const float* fc1_w  = (const float*)d_in[14];
    const float* fc1_b  = (const float*)d_in[15];
    const float* fc2_w  = (const float*)d_in[16];
    const float* fc2_b  = (const float*)d_in[17];
    const float* conv_w = (const float*)d_in[18];
    const float* L_w    = (const float*)d_in[19];
    const float* L_b    = (const float*)d_in[20];
    const float* W_w    = (const float*)d_in[21];
    const float* W_b    = (const float*)d_in[22];
    const float* v_w    = (const float*)d_in[23];
    const float* g_wih  = (const float*)d_in[24];
    const float* g_whh  = (const float*)d_in[25];
    const float* g_bih  = (const float*)d_in[26];
    const float* g_bhh  = (const float*)d_in[27];
    const float* ri_w   = (const float*)d_in[28];
    const float* ri_b   = (const float*)d_in[29];
    const float* l1_wih = (const float*)d_in[30];
    const float* l1_whh = (const float*)d_in[31];
    const float* l1_bih = (const float*)d_in[32];
    const float* l1_bhh = (const float*)d_in[33];
    const float* l2_wih = (const float*)d_in[34];
    const float* l2_whh = (const float*)d_in[35];
    const float* l2_bih = (const float*)d_in[36];
    const float* l2_bhh = (const float*)d_in[37];
    const float* mel_w  = (const float*)d_in[38];

    int r = (out_size - 808960) / 20480;
    if (r < 1) r = 1;
    if (r > 10) r = 10;

    float* out    = (float*)d_out;
    float* mels   = out;
    float* scores = out + (size_t)20480 * r;
    float* ah_out = scores + 153600;
    float* h1_out = ah_out + 65536;
    float* h2_out = h1_out + 131072;
    float* c1_out = h2_out + 131072;
    float* c2_out = c1_out + 131072;
    float* ctx_out = c2_out + 131072;

    float* ws   = (float*)d_ws;
    float* Cgi  = ws;                      // 256*768
    float* Cgh  = Cgi + 196608;            // 256*768
    float* pq   = Cgh + 196608;            // 256*256
    float* uu   = pq + 65536;              // 256*600
    float* x0   = uu + 153600;             // 256*512
    float* x1   = x0 + 131072;
    float* x2   = x1 + 131072;
    float* G0   = x2 + 131072;             // 256*2048
    float* G1   = G0 + 524288;             // 256*2048
    ushort* Lw16   = (ushort*)(G1 + 524288);  // 8192
    ushort* Xgru16 = Lw16 + 8192;             // 256*640
    ushort* Xrnn16 = Xgru16 + 163840;         // 256*832
    ushort* ah16   = Xrnn16 + 212992;         // 256*256
    ushort* ahin16 = ah16 + 65536;            // 256*256
    ushort* wcat1  = ahin16 + 65536;          // 2048*1024
    ushort* wcat2  = wcat1 + 2097152;         // 2048*1024
    ushort* gwih16 = wcat2 + 2097152;         // 768*640
    ushort* gwhh16 = gwih16 + 491520;         // 768*256
    ushort* Ww16   = gwhh16 + 196608;         // 256*256
    ushort* riw16  = Ww16 + 65536;            // 512*832
    ushort* xh1    = riw16 + 425984;          // 256*1024
    ushort* xh2    = xh1 + 262144;            // 256*1024

    prenet_kernel<<<256, 256, 0, stream>>>(pre_in, noise, fc1_w, fc1_b, fc2_w, fc2_b,
                                           ctx_in, spk, L_w, Lw16, Xgru16, Xrnn16);
    convert_all<<<5440, 256, 0, stream>>>(l1_wih, l1_whh, l2_wih, l2_whh,
                                          g_wih, g_whh, W_w, ri_w, ah_in, h1_in,
                                          wcat1, wcat2, gwih16, gwhh16,
                                          Ww16, riw16, ahin16, xh1);
    mfma_gemmN<<<dim3(8, 12), 256, 0, stream>>>(Xgru16, 640, gwih16, g_bih, Cgi, 768, nullptr);
    mfma_gemmN<<<dim3(8, 12), 256, 0, stream>>>(ahin16, 256, gwhh16, g_bhh, Cgh, 768, nullptr);
    gru_combine<<<256, 256, 0, stream>>>(Cgi, Cgh, ah_in, ah_out, ah16, Xrnn16);
    mfma_gemmN<<<dim3(8, 4), 256, 0, stream>>>(ah16, 256, Ww16, W_b, pq, 256, nullptr);
    attn_u_kernel<<<dim3(10, 256), 256, 0, stream>>>(esp, pq, cum, prv, conv_w, Lw16, L_b, v_w, uu);
    softmax_ctx_kernel<<<256, 1024, 0, stream>>>(uu, plen, enc, scores, ctx_out, Xrnn16);
    mfma_gemmN<<<dim3(8, 8), 256, 0, stream>>>(Xrnn16, 832, riw16, ri_b, x0, 512, xh1);
    mfma_gemm<<<dim3(8, 32, 2), 256, 0, stream>>>(xh1, wcat1, G0, G1);
    lstm_combine2<<<256, 512, 0, stream>>>(G0, G1, l1_bih, l1_bhh, c1_in, x0,
                                           h1_out, c1_out, x1, h2_in, xh2);
    mfma_gemm<<<dim3(8, 32, 2), 256, 0, stream>>>(xh2, wcat2, G0, G1);
    lstm_combine2<<<256, 512, 0, stream>>>(G0, G1, l2_bih, l2_bhh, c2_in, x1,
                                           h2_out, c2_out, x2, nullptr, nullptr);
    mel_kernel<<<256, 256, 0, stream>>>(x2, mel_w, r, mels);
}